// Round 1
// baseline (1373.411 us; speedup 1.0000x reference)
//
#include <hip/hip_runtime.h>

#define NN 2
#define CC 32
#define NCC 4
#define DD 96
#define WW 96
#define HH 96
#define PP (DD*WW*HH)          // 884736
#define NCP (NN*NCC*PP)        // 7077888
#define SD (WW*HH)             // 9216
#define SW HH                  // 96
#define EPS 1e-5f

__device__ __forceinline__ float wave_reduce(float v) {
#pragma unroll
    for (int off = 32; off > 0; off >>= 1) v += __shfl_down(v, off, 64);
    return v;
}

__device__ __forceinline__ float dot8(float4 a0, float4 a1, float4 b0, float4 b1) {
    return a0.x*b0.x + a0.y*b0.y + a0.z*b0.z + a0.w*b0.w
         + a1.x*b1.x + a1.y*b1.y + a1.z*b1.z + a1.w*b1.w;
}

// ---- K1: mask = sigmoid(x), float4 vectorized ----
__global__ __launch_bounds__(256) void k_sigmoid(const float4* __restrict__ x,
                                                 float4* __restrict__ m, int n4) {
    int i = blockIdx.x * 256 + threadIdx.x;
    if (i >= n4) return;
    float4 v = x[i], r;
    r.x = 1.f / (1.f + __expf(-v.x));
    r.y = 1.f / (1.f + __expf(-v.y));
    r.z = 1.f / (1.f + __expf(-v.z));
    r.w = 1.f / (1.f + __expf(-v.w));
    m[i] = r;
}

// ---- K2: 1-D pool along H (innermost). omax=maxH(mask), omin=minH(mask) ----
__global__ __launch_bounds__(256) void k_poolH(const float* __restrict__ m,
                                               float* __restrict__ omax,
                                               float* __restrict__ omin) {
    int i = blockIdx.x * 256 + threadIdx.x;
    int h = i % HH;
    float mx = -1e30f, mn = 1e30f;
#pragma unroll
    for (int dh = -2; dh <= 2; ++dh) {
        int hh = h + dh;
        if (hh >= 0 && hh < HH) {
            float v = m[i + dh];
            mx = fmaxf(mx, v); mn = fminf(mn, v);
        }
    }
    omax[i] = mx; omin[i] = mn;
}

// ---- K3: pool along W. omax = maxW(maxH); iomin = min(iomin, minW(mask)) ----
__global__ __launch_bounds__(256) void k_poolW(const float* __restrict__ tmax,
                                               const float* __restrict__ m,
                                               float* __restrict__ omax,
                                               float* __restrict__ iomin) {
    int i = blockIdx.x * 256 + threadIdx.x;
    int w = (i / HH) % WW;
    float mx = -1e30f, mn = 1e30f;
#pragma unroll
    for (int dw = -2; dw <= 2; ++dw) {
        int wi = w + dw;
        if (wi >= 0 && wi < WW) {
            mx = fmaxf(mx, tmax[i + dw*SW]);
            mn = fminf(mn, m[i + dw*SW]);
        }
    }
    omax[i] = mx;
    iomin[i] = fminf(iomin[i], mn);
}

// ---- K4: pool along D. dil = maxD(maxHW); ero = min(min12, minD(mask)).
//      Also accumulates esum/dsum per (n,k). Block = 1024 contiguous elems
//      (aligned inside one (n,k) plane since 1024 | P). ----
__global__ __launch_bounds__(256) void k_poolD(const float* __restrict__ tmax,
                                               const float* __restrict__ m,
                                               const float* __restrict__ min12,
                                               float* __restrict__ dil,
                                               float* __restrict__ ero,
                                               float* __restrict__ esum,
                                               float* __restrict__ dsum) {
    int base = blockIdx.x * 1024;
    int nk = base / PP;
    float ae = 0.f, ad = 0.f;
#pragma unroll
    for (int j = 0; j < 4; ++j) {
        int i = base + threadIdx.x + j*256;
        int d = (i / SD) % DD;
        float mx = -1e30f, mn = 1e30f;
#pragma unroll
        for (int dd = -2; dd <= 2; ++dd) {
            int di = d + dd;
            if (di >= 0 && di < DD) {
                mx = fmaxf(mx, tmax[i + dd*SD]);
                mn = fminf(mn, m[i + dd*SD]);
            }
        }
        float ev = fminf(min12[i], mn);
        dil[i] = mx; ero[i] = ev;
        ae += ev; ad += mx;
    }
    ae = wave_reduce(ae); ad = wave_reduce(ad);
    __shared__ float se, sdv;
    if (threadIdx.x == 0) { se = 0.f; sdv = 0.f; }
    __syncthreads();
    if ((threadIdx.x & 63) == 0) { atomicAdd(&se, ae); atomicAdd(&sdv, ad); }
    __syncthreads();
    if (threadIdx.x == 0) { atomicAdd(&esum[nk], se); atomicAdd(&dsum[nk], sdv); }
}

// ---- K5: split-K dots. Per (n,c): dot_e[k] = <feat_c, ero_k>, dot_d[k] = <feat_c, dil_k>,
//      fsum = sum(feat_c). Block = 2048 contiguous p within one n; 8 p per thread. ----
__global__ __launch_bounds__(256, 2) void k_dots(const float* __restrict__ feat,
                                                 const float* __restrict__ ero,
                                                 const float* __restrict__ dil,
                                                 float* __restrict__ dot_e,
                                                 float* __restrict__ dot_d,
                                                 float* __restrict__ fsum) {
    const int chunks_per_n = PP / 2048;   // 432
    int b = blockIdx.x;
    int n = b / chunks_per_n;
    int p0 = (b % chunks_per_n) * 2048 + threadIdx.x * 8;

    float4 e[NCC][2], dv[NCC][2];
#pragma unroll
    for (int k = 0; k < NCC; ++k) {
        const float* pe = ero + ((size_t)(n*NCC + k))*PP + p0;
        const float* pd = dil + ((size_t)(n*NCC + k))*PP + p0;
        e[k][0]  = *(const float4*)pe;     e[k][1]  = *(const float4*)(pe + 4);
        dv[k][0] = *(const float4*)pd;     dv[k][1] = *(const float4*)(pd + 4);
    }

    __shared__ float sacc[CC][9];
    for (int t = threadIdx.x; t < CC*9; t += 256) ((float*)sacc)[t] = 0.f;
    __syncthreads();

    for (int c = 0; c < CC; ++c) {
        const float* pf = feat + ((size_t)(n*CC + c))*PP + p0;
        float4 fa = *(const float4*)pf, fb = *(const float4*)(pf + 4);
        float vals[9];
#pragma unroll
        for (int k = 0; k < NCC; ++k) {
            vals[k]     = dot8(fa, fb, e[k][0],  e[k][1]);
            vals[4 + k] = dot8(fa, fb, dv[k][0], dv[k][1]);
        }
        vals[8] = fa.x + fa.y + fa.z + fa.w + fb.x + fb.y + fb.z + fb.w;
#pragma unroll
        for (int q = 0; q < 9; ++q) {
            float r = wave_reduce(vals[q]);
            if ((threadIdx.x & 63) == 0) atomicAdd(&sacc[c][q], r);
        }
    }
    __syncthreads();
    for (int t = threadIdx.x; t < CC*9; t += 256) {
        int c = t / 9, q = t % 9;
        float v = sacc[c][q];
        if (q < 4)      atomicAdd(&dot_e[(n*CC + c)*NCC + q], v);
        else if (q < 8) atomicAdd(&dot_d[(n*CC + c)*NCC + (q - 4)], v);
        else            atomicAdd(&fsum[n*CC + c], v);
    }
}

// ---- K6: cluster[n][k][c][{fore,back}] from the dots ----
__global__ __launch_bounds__(256) void k_cluster(const float* __restrict__ dot_e,
                                                 const float* __restrict__ dot_d,
                                                 const float* __restrict__ fsum,
                                                 const float* __restrict__ esum,
                                                 const float* __restrict__ dsum,
                                                 float* __restrict__ cluster) {
    int t = threadIdx.x;              // 256 = N*NC*C
    int n = t / (NCC*CC);
    int k = (t / CC) % NCC;
    int c = t % CC;
    float de = dot_e[(n*CC + c)*NCC + k];
    float dd = dot_d[(n*CC + c)*NCC + k];
    float fs = fsum[n*CC + c];
    float es = esum[n*NCC + k] + EPS;
    float ds = dsum[n*NCC + k] + EPS;
    float bs = (float)PP - dsum[n*NCC + k] + EPS;
    float ec = de / es, dc = dd / ds, bc = (fs - dd) / bs;
    cluster[((n*NCC + k)*CC + c)*2 + 0] = ec + dc;
    cluster[((n*NCC + k)*CC + c)*2 + 1] = bc;
}

// ---- K7: attention + out + BN partial sums. Block = 1024 p within one n, 4 p/thread. ----
__global__ __launch_bounds__(256, 2) void k_attn(const float* __restrict__ feat,
                                                 const float* __restrict__ cluster,
                                                 const float* __restrict__ kptr,
                                                 float* __restrict__ out,
                                                 float* __restrict__ bnsum,
                                                 float* __restrict__ bnsq) {
    const int blocks_per_n = PP / 1024;  // 864
    int b = blockIdx.x;
    int n = b / blocks_per_n;
    int pbase = (b % blocks_per_n) * 1024;

    __shared__ float cl[NCC*CC*2];       // 256 floats
    cl[threadIdx.x] = cluster[n*NCC*CC*2 + threadIdx.x];
    __syncthreads();
    float kk = kptr[0];

    float bs_[CC], bq[CC];
#pragma unroll
    for (int c = 0; c < CC; ++c) { bs_[c] = 0.f; bq[c] = 0.f; }

    const float* fb = feat + (size_t)n*CC*PP + pbase;
    float* ob = out + (size_t)n*CC*PP + pbase;

    for (int it = 0; it < 4; ++it) {
        int p = threadIdx.x + it*256;
        float f[CC], s[8];
#pragma unroll
        for (int q = 0; q < 8; ++q) s[q] = 0.f;
#pragma unroll
        for (int c = 0; c < CC; ++c) f[c] = fb[(size_t)c*PP + p];
#pragma unroll
        for (int c = 0; c < CC; ++c) {
#pragma unroll
            for (int k = 0; k < NCC; ++k) {
                s[k*2]     += f[c] * cl[(k*CC + c)*2];
                s[k*2 + 1] += f[c] * cl[(k*CC + c)*2 + 1];
            }
        }
        float w[8];
#pragma unroll
        for (int k = 0; k < NCC; ++k) {
            float a0 = s[k*2], a1 = s[k*2 + 1];
            float mx = fmaxf(a0, a1);
            float e0 = __expf(a0 - mx), e1 = __expf(a1 - mx);
            float r = 1.f / (e0 + e1);
            w[k*2] = e0*r; w[k*2 + 1] = e1*r;
        }
#pragma unroll
        for (int c = 0; c < CC; ++c) {
            float a = 0.f;
#pragma unroll
            for (int k = 0; k < NCC; ++k)
                a += w[k*2]*cl[(k*CC + c)*2] + w[k*2 + 1]*cl[(k*CC + c)*2 + 1];
            float o = 5.f*f[c] + kk*a;
            ob[(size_t)c*PP + p] = o;
            bs_[c] += o; bq[c] += o*o;
        }
    }

    __shared__ float sb[2*CC];
    for (int t = threadIdx.x; t < 2*CC; t += 256) sb[t] = 0.f;
    __syncthreads();
#pragma unroll
    for (int c = 0; c < CC; ++c) {
        float rs = wave_reduce(bs_[c]);
        float rq = wave_reduce(bq[c]);
        if ((threadIdx.x & 63) == 0) { atomicAdd(&sb[c], rs); atomicAdd(&sb[CC + c], rq); }
    }
    __syncthreads();
    for (int t = threadIdx.x; t < 2*CC; t += 256) {
        if (t < CC) atomicAdd(&bnsum[t], sb[t]);
        else        atomicAdd(&bnsq[t - CC], sb[t]);
    }
}

// ---- K8: BN finalize: per-channel scale/shift ----
__global__ __launch_bounds__(64) void k_bnfin(const float* __restrict__ bnsum,
                                              const float* __restrict__ bnsq,
                                              const float* __restrict__ wgt,
                                              const float* __restrict__ bias,
                                              float* __restrict__ scale,
                                              float* __restrict__ shift) {
    int c = threadIdx.x;
    if (c < CC) {
        float inv_n = 1.f / (float)((size_t)NN * PP);
        float mean = bnsum[c] * inv_n;
        float var  = bnsq[c] * inv_n - mean*mean;
        float inv  = 1.f / sqrtf(var + EPS);
        float sc = wgt[c] * inv;
        scale[c] = sc;
        shift[c] = bias[c] - mean*sc;
    }
}

// ---- K9: apply BN in-place on out, float4 vectorized. c uniform per block. ----
__global__ __launch_bounds__(256) void k_bnapply(float4* __restrict__ out,
                                                 const float* __restrict__ scale,
                                                 const float* __restrict__ shift,
                                                 int n4) {
    int i = blockIdx.x * 256 + threadIdx.x;
    if (i >= n4) return;
    int c = ((blockIdx.x * 1024) / PP) % CC;   // 1024 elems per block, 1024 | P
    float sc = scale[c], sh = shift[c];
    float4 v = out[i];
    v.x = v.x*sc + sh; v.y = v.y*sc + sh; v.z = v.z*sc + sh; v.w = v.w*sc + sh;
    out[i] = v;
}

extern "C" void kernel_launch(void* const* d_in, const int* in_sizes, int n_in,
                              void* d_out, int out_size, void* d_ws, size_t ws_size,
                              hipStream_t stream) {
    const float* feat = (const float*)d_in[0];
    const float* x    = (const float*)d_in[1];
    const float* kp   = (const float*)d_in[2];
    const float* bnw  = (const float*)d_in[3];
    const float* bnb  = (const float*)d_in[4];
    float* out = (float*)d_out;
    float* ws  = (float*)d_ws;

    float* mask = ws;
    float* t0   = ws + 1*(size_t)NCP;
    float* t1   = ws + 2*(size_t)NCP;
    float* t2   = ws + 3*(size_t)NCP;
    float* dil  = ws + 4*(size_t)NCP;
    float* ero  = ws + 5*(size_t)NCP;
    float* acc  = ws + 6*(size_t)NCP;
    float* dot_e   = acc;          // 256
    float* dot_d   = acc + 256;    // 256
    float* fsum    = acc + 512;    // 64
    float* esum    = acc + 576;    // 8
    float* dsum    = acc + 584;    // 8
    float* bnsum   = acc + 592;    // 32
    float* bnsq    = acc + 624;    // 32
    float* cluster = acc + 656;    // 512
    float* scale   = acc + 1168;   // 32
    float* shift   = acc + 1200;   // 32

    hipMemsetAsync(acc, 0, 1232 * sizeof(float), stream);

    k_sigmoid<<<NCP/1024, 256, 0, stream>>>((const float4*)x, (float4*)mask, NCP/4);
    k_poolH  <<<NCP/256, 256, 0, stream>>>(mask, t0, t1);
    k_poolW  <<<NCP/256, 256, 0, stream>>>(t0, mask, t2, t1);
    k_poolD  <<<NCP/1024, 256, 0, stream>>>(t2, mask, t1, dil, ero, esum, dsum);
    k_dots   <<<NN*(PP/2048), 256, 0, stream>>>(feat, ero, dil, dot_e, dot_d, fsum);
    k_cluster<<<1, 256, 0, stream>>>(dot_e, dot_d, fsum, esum, dsum, cluster);
    k_attn   <<<NN*(PP/1024), 256, 0, stream>>>(feat, cluster, kp, out, bnsum, bnsq);
    k_bnfin  <<<1, 64, 0, stream>>>(bnsum, bnsq, bnw, bnb, scale, shift);
    k_bnapply<<<(NN*(size_t)CC*PP/4)/256, 256, 0, stream>>>((float4*)out, scale, shift, NN*CC*PP/4);
}

// Round 2
// 952.356 us; speedup vs baseline: 1.4421x; 1.4421x over previous
//
#include <hip/hip_runtime.h>

#define NN 2
#define CC 32
#define NCC 4
#define DD 96
#define WW 96
#define HH 96
#define PP (DD*WW*HH)          // 884736
#define NCP (NN*NCC*PP)        // 7077888
#define SD (WW*HH)             // 9216
#define SW HH                  // 96
#define EPS 1e-5f
#define BIGF 1e30f

__device__ __forceinline__ float wave_reduce(float v) {
#pragma unroll
    for (int off = 32; off > 0; off >>= 1) v += __shfl_down(v, off, 64);
    return v;
}

__device__ __forceinline__ float dot8(float4 a0, float4 a1, float4 b0, float4 b1) {
    return a0.x*b0.x + a0.y*b0.y + a0.z*b0.z + a0.w*b0.w
         + a1.x*b1.x + a1.y*b1.y + a1.z*b1.z + a1.w*b1.w;
}

__device__ __forceinline__ float sigf(float v) { return 1.f / (1.f + __expf(-v)); }

// ---- K1: fused sigmoid + 1-D pool along H. Thread owns 4 consecutive h.
//      mask=sigmoid(x); omax=maxH(mask); omin=minH(mask). ----
__global__ __launch_bounds__(256) void k_poolH(const float* __restrict__ x,
                                               float* __restrict__ mask,
                                               float* __restrict__ omax,
                                               float* __restrict__ omin) {
    int i = (blockIdx.x * 256 + threadIdx.x) * 4;
    int h0 = i % HH;                       // multiple of 4
    float4 xv = *(const float4*)(x + i);
    float v0 = sigf(xv.x), v1 = sigf(xv.y), v2 = sigf(xv.z), v3 = sigf(xv.w);
    float aM = -BIGF, bM = -BIGF, cM = -BIGF, dM = -BIGF;
    float am =  BIGF, bm =  BIGF, cm =  BIGF, dm =  BIGF;
    if (h0 > 0) {
        float t0 = sigf(x[i-2]), t1 = sigf(x[i-1]);
        aM = t0; am = t0; bM = t1; bm = t1;
    }
    if (h0 < 92) {
        float t0 = sigf(x[i+4]), t1 = sigf(x[i+5]);
        cM = t0; cm = t0; dM = t1; dm = t1;
    }
    float4 mo, mx, mn;
    mo.x = v0; mo.y = v1; mo.z = v2; mo.w = v3;
    mx.x = fmaxf(fmaxf(aM, bM), fmaxf(fmaxf(v0, v1), v2));
    mx.y = fmaxf(bM, fmaxf(fmaxf(v0, v1), fmaxf(v2, v3)));
    mx.z = fmaxf(fmaxf(fmaxf(v0, v1), fmaxf(v2, v3)), cM);
    mx.w = fmaxf(fmaxf(v1, v2), fmaxf(v3, fmaxf(cM, dM)));
    mn.x = fminf(fminf(am, bm), fminf(fminf(v0, v1), v2));
    mn.y = fminf(bm, fminf(fminf(v0, v1), fminf(v2, v3)));
    mn.z = fminf(fminf(fminf(v0, v1), fminf(v2, v3)), cm);
    mn.w = fminf(fminf(v1, v2), fminf(v3, fminf(cm, dm)));
    *(float4*)(mask + i) = mo;
    *(float4*)(omax + i) = mx;
    *(float4*)(omin + i) = mn;
}

// ---- K2: pool along W. omax = maxW(tmax); iomin = min(iomin, minW(mask)). ----
__global__ __launch_bounds__(256) void k_poolW(const float* __restrict__ tmax,
                                               const float* __restrict__ m,
                                               float* __restrict__ omax,
                                               float* __restrict__ iomin) {
    int i = (blockIdx.x * 256 + threadIdx.x) * 4;
    int w = (i / HH) % WW;
    float4 mx = make_float4(-BIGF, -BIGF, -BIGF, -BIGF);
    float4 mn = make_float4( BIGF,  BIGF,  BIGF,  BIGF);
#pragma unroll
    for (int dw = -2; dw <= 2; ++dw) {
        int wi = w + dw;
        if (wi >= 0 && wi < WW) {
            float4 a = *(const float4*)(tmax + i + dw*SW);
            float4 b = *(const float4*)(m + i + dw*SW);
            mx.x = fmaxf(mx.x, a.x); mx.y = fmaxf(mx.y, a.y);
            mx.z = fmaxf(mx.z, a.z); mx.w = fmaxf(mx.w, a.w);
            mn.x = fminf(mn.x, b.x); mn.y = fminf(mn.y, b.y);
            mn.z = fminf(mn.z, b.z); mn.w = fminf(mn.w, b.w);
        }
    }
    float4 prev = *(const float4*)(iomin + i);
    prev.x = fminf(prev.x, mn.x); prev.y = fminf(prev.y, mn.y);
    prev.z = fminf(prev.z, mn.z); prev.w = fminf(prev.w, mn.w);
    *(float4*)(omax + i) = mx;
    *(float4*)(iomin + i) = prev;
}

// ---- K3: pool along D. dil = maxD(tmax); ero = min(min12, minD(mask));
//      accumulates esum/dsum per (n,k). Block = 1024 contiguous elems. ----
__global__ __launch_bounds__(256) void k_poolD(const float* __restrict__ tmax,
                                               const float* __restrict__ m,
                                               const float* __restrict__ min12,
                                               float* __restrict__ dil,
                                               float* __restrict__ ero,
                                               float* __restrict__ esum,
                                               float* __restrict__ dsum) {
    int base = blockIdx.x * 1024;
    int nk = base / PP;
    int i = base + threadIdx.x * 4;
    int d = (i / SD) % DD;
    float4 mx = make_float4(-BIGF, -BIGF, -BIGF, -BIGF);
    float4 mn = make_float4( BIGF,  BIGF,  BIGF,  BIGF);
#pragma unroll
    for (int dd = -2; dd <= 2; ++dd) {
        int di = d + dd;
        if (di >= 0 && di < DD) {
            float4 a = *(const float4*)(tmax + i + dd*SD);
            float4 b = *(const float4*)(m + i + dd*SD);
            mx.x = fmaxf(mx.x, a.x); mx.y = fmaxf(mx.y, a.y);
            mx.z = fmaxf(mx.z, a.z); mx.w = fmaxf(mx.w, a.w);
            mn.x = fminf(mn.x, b.x); mn.y = fminf(mn.y, b.y);
            mn.z = fminf(mn.z, b.z); mn.w = fminf(mn.w, b.w);
        }
    }
    float4 m12 = *(const float4*)(min12 + i);
    float4 ev;
    ev.x = fminf(m12.x, mn.x); ev.y = fminf(m12.y, mn.y);
    ev.z = fminf(m12.z, mn.z); ev.w = fminf(m12.w, mn.w);
    *(float4*)(dil + i) = mx;
    *(float4*)(ero + i) = ev;
    float ae = ev.x + ev.y + ev.z + ev.w;
    float ad = mx.x + mx.y + mx.z + mx.w;
    ae = wave_reduce(ae); ad = wave_reduce(ad);
    __shared__ float se, sdv;
    if (threadIdx.x == 0) { se = 0.f; sdv = 0.f; }
    __syncthreads();
    if ((threadIdx.x & 63) == 0) { atomicAdd(&se, ae); atomicAdd(&sdv, ad); }
    __syncthreads();
    if (threadIdx.x == 0) { atomicAdd(&esum[nk], se); atomicAdd(&dsum[nk], sdv); }
}

// ---- K4: split-K dots. Per (n,c): dot_e[k], dot_d[k], fsum. ----
__global__ __launch_bounds__(256, 2) void k_dots(const float* __restrict__ feat,
                                                 const float* __restrict__ ero,
                                                 const float* __restrict__ dil,
                                                 float* __restrict__ dot_e,
                                                 float* __restrict__ dot_d,
                                                 float* __restrict__ fsum) {
    const int chunks_per_n = PP / 2048;   // 432
    int b = blockIdx.x;
    int n = b / chunks_per_n;
    int p0 = (b % chunks_per_n) * 2048 + threadIdx.x * 8;

    float4 e[NCC][2], dv[NCC][2];
#pragma unroll
    for (int k = 0; k < NCC; ++k) {
        const float* pe = ero + ((size_t)(n*NCC + k))*PP + p0;
        const float* pd = dil + ((size_t)(n*NCC + k))*PP + p0;
        e[k][0]  = *(const float4*)pe;     e[k][1]  = *(const float4*)(pe + 4);
        dv[k][0] = *(const float4*)pd;     dv[k][1] = *(const float4*)(pd + 4);
    }

    __shared__ float sacc[CC][9];
    for (int t = threadIdx.x; t < CC*9; t += 256) ((float*)sacc)[t] = 0.f;
    __syncthreads();

    for (int c = 0; c < CC; ++c) {
        const float* pf = feat + ((size_t)(n*CC + c))*PP + p0;
        float4 fa = *(const float4*)pf, fb = *(const float4*)(pf + 4);
        float vals[9];
#pragma unroll
        for (int k = 0; k < NCC; ++k) {
            vals[k]     = dot8(fa, fb, e[k][0],  e[k][1]);
            vals[4 + k] = dot8(fa, fb, dv[k][0], dv[k][1]);
        }
        vals[8] = fa.x + fa.y + fa.z + fa.w + fb.x + fb.y + fb.z + fb.w;
#pragma unroll
        for (int q = 0; q < 9; ++q) {
            float r = wave_reduce(vals[q]);
            if ((threadIdx.x & 63) == 0) atomicAdd(&sacc[c][q], r);
        }
    }
    __syncthreads();
    for (int t = threadIdx.x; t < CC*9; t += 256) {
        int c = t / 9, q = t % 9;
        float v = sacc[c][q];
        if (q < 4)      atomicAdd(&dot_e[(n*CC + c)*NCC + q], v);
        else if (q < 8) atomicAdd(&dot_d[(n*CC + c)*NCC + (q - 4)], v);
        else            atomicAdd(&fsum[n*CC + c], v);
    }
}

// ---- K5: cluster[n][k][c][{fore,back}] ----
__global__ __launch_bounds__(256) void k_cluster(const float* __restrict__ dot_e,
                                                 const float* __restrict__ dot_d,
                                                 const float* __restrict__ fsum,
                                                 const float* __restrict__ esum,
                                                 const float* __restrict__ dsum,
                                                 float* __restrict__ cluster) {
    int t = threadIdx.x;              // 256 = N*NC*C
    int n = t / (NCC*CC);
    int k = (t / CC) % NCC;
    int c = t % CC;
    float de = dot_e[(n*CC + c)*NCC + k];
    float dd = dot_d[(n*CC + c)*NCC + k];
    float fs = fsum[n*CC + c];
    float es = esum[n*NCC + k] + EPS;
    float ds = dsum[n*NCC + k] + EPS;
    float bs = (float)PP - dsum[n*NCC + k] + EPS;
    float ec = de / es, dc = dd / ds, bc = (fs - dd) / bs;
    cluster[((n*NCC + k)*CC + c)*2 + 0] = ec + dc;
    cluster[((n*NCC + k)*CC + c)*2 + 1] = bc;
}

// ---- K6: attention + out, LDS-tiled. Block = 256 p, all 32 c. ----
__global__ __launch_bounds__(256) void k_attn(const float* __restrict__ feat,
                                              const float* __restrict__ cluster,
                                              const float* __restrict__ kptr,
                                              float* __restrict__ out) {
    __shared__ float cl[NCC*CC*2];        // 256
    __shared__ float tile[CC*256];        // 32 KB
    const int tiles_per_n = PP / 256;     // 3456
    int b = blockIdx.x;
    int n = b / tiles_per_n;
    int p0 = (b % tiles_per_n) * 256;
    int t = threadIdx.x;
    int wv = t >> 6, ln = t & 63;

    cl[t] = cluster[n*NCC*CC*2 + t];
    const float* fb = feat + (size_t)n*CC*PP + p0;
#pragma unroll
    for (int j = 0; j < 8; ++j) {
        int c = wv*8 + j;
        *(float4*)&tile[c*256 + ln*4] = *(const float4*)(fb + (size_t)c*PP + ln*4);
    }
    __syncthreads();

    float kk = kptr[0];
    float f[CC], s[8];
#pragma unroll
    for (int q = 0; q < 8; ++q) s[q] = 0.f;
#pragma unroll
    for (int c = 0; c < CC; ++c) {
        float fv = tile[c*256 + t];
        f[c] = fv;
#pragma unroll
        for (int k = 0; k < NCC; ++k) {
            s[2*k]   += fv * cl[(k*CC + c)*2];
            s[2*k+1] += fv * cl[(k*CC + c)*2 + 1];
        }
    }
    float w[8];
#pragma unroll
    for (int k = 0; k < NCC; ++k) {
        float mx = fmaxf(s[2*k], s[2*k+1]);
        float e0 = __expf(s[2*k] - mx), e1 = __expf(s[2*k+1] - mx);
        float r = 1.f / (e0 + e1);
        w[2*k] = e0*r; w[2*k+1] = e1*r;
    }
    // thread t only touches column t below — no barrier needed before overwrite
#pragma unroll
    for (int c = 0; c < CC; ++c) {
        float a = 0.f;
#pragma unroll
        for (int k = 0; k < NCC; ++k)
            a += w[2*k]*cl[(k*CC + c)*2] + w[2*k+1]*cl[(k*CC + c)*2 + 1];
        tile[c*256 + t] = 5.f*f[c] + kk*a;
    }
    __syncthreads();
    float* ob = out + (size_t)n*CC*PP + p0;
#pragma unroll
    for (int j = 0; j < 8; ++j) {
        int c = wv*8 + j;
        *(float4*)(ob + (size_t)c*PP + ln*4) = *(const float4*)&tile[c*256 + ln*4];
    }
}

// ---- K7: BN stats over out. Block = (c, slice). ----
__global__ __launch_bounds__(256) void k_bnstats(const float* __restrict__ out,
                                                 float* __restrict__ bnsum,
                                                 float* __restrict__ bnsq) {
    const int SPLIT = 32;
    const int CHUNK = PP / SPLIT;         // 27648
    int c = blockIdx.x / SPLIT;
    int s = blockIdx.x % SPLIT;
    float sum = 0.f, sq = 0.f;
#pragma unroll
    for (int n = 0; n < NN; ++n) {
        const float* b = out + (size_t)n*CC*PP + (size_t)c*PP + s*CHUNK;
        for (int i = threadIdx.x*4; i < CHUNK; i += 1024) {
            float4 v = *(const float4*)(b + i);
            sum += v.x + v.y + v.z + v.w;
            sq  += v.x*v.x + v.y*v.y + v.z*v.z + v.w*v.w;
        }
    }
    sum = wave_reduce(sum); sq = wave_reduce(sq);
    __shared__ float ss, sg;
    if (threadIdx.x == 0) { ss = 0.f; sg = 0.f; }
    __syncthreads();
    if ((threadIdx.x & 63) == 0) { atomicAdd(&ss, sum); atomicAdd(&sg, sq); }
    __syncthreads();
    if (threadIdx.x == 0) { atomicAdd(&bnsum[c], ss); atomicAdd(&bnsq[c], sg); }
}

// ---- K8: BN finalize ----
__global__ __launch_bounds__(64) void k_bnfin(const float* __restrict__ bnsum,
                                              const float* __restrict__ bnsq,
                                              const float* __restrict__ wgt,
                                              const float* __restrict__ bias,
                                              float* __restrict__ scale,
                                              float* __restrict__ shift) {
    int c = threadIdx.x;
    if (c < CC) {
        float inv_n = 1.f / (float)((size_t)NN * PP);
        float mean = bnsum[c] * inv_n;
        float var  = bnsq[c] * inv_n - mean*mean;
        float inv  = 1.f / sqrtf(var + EPS);
        float sc = wgt[c] * inv;
        scale[c] = sc;
        shift[c] = bias[c] - mean*sc;
    }
}

// ---- K9: apply BN in-place, float4 ----
__global__ __launch_bounds__(256) void k_bnapply(float4* __restrict__ out,
                                                 const float* __restrict__ scale,
                                                 const float* __restrict__ shift,
                                                 int n4) {
    int i = blockIdx.x * 256 + threadIdx.x;
    if (i >= n4) return;
    int c = ((blockIdx.x * 1024) / PP) % CC;   // 1024 elems per block, 1024 | P
    float sc = scale[c], sh = shift[c];
    float4 v = out[i];
    v.x = v.x*sc + sh; v.y = v.y*sc + sh; v.z = v.z*sc + sh; v.w = v.w*sc + sh;
    out[i] = v;
}

extern "C" void kernel_launch(void* const* d_in, const int* in_sizes, int n_in,
                              void* d_out, int out_size, void* d_ws, size_t ws_size,
                              hipStream_t stream) {
    const float* feat = (const float*)d_in[0];
    const float* x    = (const float*)d_in[1];
    const float* kp   = (const float*)d_in[2];
    const float* bnw  = (const float*)d_in[3];
    const float* bnb  = (const float*)d_in[4];
    float* out = (float*)d_out;
    float* ws  = (float*)d_ws;

    float* mask = ws;
    float* t0   = ws + 1*(size_t)NCP;
    float* t1   = ws + 2*(size_t)NCP;
    float* t2   = ws + 3*(size_t)NCP;
    float* dil  = ws + 4*(size_t)NCP;
    float* ero  = ws + 5*(size_t)NCP;
    float* acc  = ws + 6*(size_t)NCP;
    float* dot_e   = acc;          // 256
    float* dot_d   = acc + 256;    // 256
    float* fsum    = acc + 512;    // 64
    float* esum    = acc + 576;    // 8
    float* dsum    = acc + 584;    // 8
    float* bnsum   = acc + 592;    // 32
    float* bnsq    = acc + 624;    // 32
    float* cluster = acc + 656;    // 512
    float* scale   = acc + 1168;   // 32
    float* shift   = acc + 1200;   // 32

    hipMemsetAsync(acc, 0, 1232 * sizeof(float), stream);

    k_poolH  <<<NCP/1024, 256, 0, stream>>>(x, mask, t0, t1);
    k_poolW  <<<NCP/1024, 256, 0, stream>>>(t0, mask, t2, t1);
    k_poolD  <<<NCP/1024, 256, 0, stream>>>(t2, mask, t1, dil, ero, esum, dsum);
    k_dots   <<<NN*(PP/2048), 256, 0, stream>>>(feat, ero, dil, dot_e, dot_d, fsum);
    k_cluster<<<1, 256, 0, stream>>>(dot_e, dot_d, fsum, esum, dsum, cluster);
    k_attn   <<<NN*(PP/256), 256, 0, stream>>>(feat, cluster, kp, out);
    k_bnstats<<<CC*32, 256, 0, stream>>>(out, bnsum, bnsq);
    k_bnfin  <<<1, 64, 0, stream>>>(bnsum, bnsq, bnw, bnb, scale, shift);
    k_bnapply<<<(NN*(size_t)CC*PP/4)/256, 256, 0, stream>>>((float4*)out, scale, shift, NN*CC*PP/4);
}